// Round 1
// baseline (44.455 us; speedup 1.0000x reference)
//
#include <hip/hip_runtime.h>
#include <math.h>

// SPSA on f(x) = x0^2 + Q*x1^2, Q=8. Exact algebra:
//   f(x+ck*d) - f(x-ck*d) = 4*ck*(d0*x0 + Q*d1*x1)      (d = +-1)
//   ghat0 = 2*(x0 + Q*s*x1),  ghat1 = 2*s*(x0 + Q*s*x1),  s = d0*d1
//   x0' = x0 - 2*ak*u,  x1' = x1 - 2*ak*s*u,  u = x0 + Q*s*x1
// ck cancels exactly; per-step = 3 fma + sign xors. Coef table nw[k] = -2*ak.

#define BLK 64
#define UNR 25   // int2 loads per chunk per lane (50 VGPR/buffer)

__global__ __launch_bounds__(BLK, 1) void spsa_kernel(
    const float2* __restrict__ X0,
    const int2*   __restrict__ bits,   // (n, bs) int2 of {0,1} bits
    const float*  __restrict__ a_arr,
    float2*       __restrict__ out,
    int n, int bs, int A)
{
    __shared__ float s_nw[1024];       // n <= 1024 (n = 1000 here)

    const int tid = threadIdx.x;
    const int b   = blockIdx.x * BLK + tid;
    const bool act = (b < bs);

    const int nch = n / UNR;           // full chunks
    const int2* p = bits + b;          // element k at p[k*bs]

    int2 bufA[UNR], bufB[UNR];

    // Issue prologue loads FIRST so HBM latency hides under table setup.
    if (act && nch > 0) {
        #pragma unroll
        for (int j = 0; j < UNR; ++j) bufA[j] = p[j * bs];
    }
    float2 xin = make_float2(0.f, 0.f);
    if (act) xin = X0[b];

    // Per-block coefficient table: nw[k] = -2 * a[k] / (k+2+A)^0.602
    for (int k = tid; k < n; k += BLK) {
        float base = (float)(k + 2 + A);
        s_nw[k] = -2.0f * a_arr[k] / powf(base, 0.602f);
    }
    __syncthreads();
    if (!act) return;

    float x0 = xin.x * 20.0f - 10.0f;
    float x1 = xin.y * 20.0f - 10.0f;

    auto step = [&x0, &x1](int2 d, float nw) {
        unsigned sb = ((unsigned)(d.x ^ d.y)) << 31;      // sign of s = d0*d1
        float qs  = __uint_as_float(0x41000000u ^ sb);    // +-8.0
        float nws = __uint_as_float(__float_as_uint(nw) ^ sb); // -(2ak*s)
        float u = fmaf(qs, x1, x0);                       // x0 + Q*s*x1
        x0 = fmaf(nw,  u, x0);
        x1 = fmaf(nws, u, x1);
    };

    // Software-pipelined, double-buffered main loop (static reg indexing only).
    for (int ch = 0; ch < nch; ch += 2) {
        if (ch + 1 < nch) {
            const int2* q = p + (ch + 1) * UNR * bs;
            #pragma unroll
            for (int j = 0; j < UNR; ++j) bufB[j] = q[j * bs];
        }
        {
            const int kb = ch * UNR;
            #pragma unroll
            for (int j = 0; j < UNR; ++j) step(bufA[j], s_nw[kb + j]);
        }
        if (ch + 2 < nch) {
            const int2* q = p + (ch + 2) * UNR * bs;
            #pragma unroll
            for (int j = 0; j < UNR; ++j) bufA[j] = q[j * bs];
        }
        if (ch + 1 < nch) {
            const int kb = (ch + 1) * UNR;
            #pragma unroll
            for (int j = 0; j < UNR; ++j) step(bufB[j], s_nw[kb + j]);
        }
    }
    // Remainder (n % UNR; 0 for n=1000)
    for (int k = nch * UNR; k < n; ++k) step(p[k * bs], s_nw[k]);

    out[b] = make_float2(x0, x1);
}

extern "C" void kernel_launch(void* const* d_in, const int* in_sizes, int n_in,
                              void* d_out, int out_size, void* d_ws, size_t ws_size,
                              hipStream_t stream) {
    const float2* X0   = (const float2*)d_in[0];
    const float*  a    = (const float*) d_in[1];
    // d_in[2] = c (cancels exactly, unused); d_in[4] = num_itr (use in_sizes)
    const int2*   bits = (const int2*)  d_in[3];
    float2*       out  = (float2*)d_out;

    const int bs = in_sizes[0] / 2;
    const int n  = in_sizes[1];
    const int A  = (int)floor(0.1 * (double)n);   // matches np.floor(0.1*num_itr)

    const int grid = (bs + BLK - 1) / BLK;
    spsa_kernel<<<grid, BLK, 0, stream>>>(X0, bits, a, out, n, bs, A);
}